// Round 13
// baseline (242.988 us; speedup 1.0000x reference)
//
#include <hip/hip_runtime.h>
#include <hip/hip_bf16.h>

// ---------------------------------------------------------------------------
// GraphSAGE 3-layer forward. bf16 MFMA GEMMs (f32 accum).
// R13 structure:
//  - GEMMs: B staged ONCE in LDS (one barrier total), col-half split,
//    A register-prefetched 3-deep, persistent waves. (R8 quarter-split paid
//    4x A-traffic with 1-deep prefetch -> ~2 TB/s; this targets ~5 TB/s on 2x.)
//  - L0/L1 aggregation inputs in fp8-e4m3 (flush-subnormal): halves the
//    L3-bound gather bytes. Packed bit-decode to f16 + v_pk_add_f16.
//  - log_softmax fused into the 64-d segmean; T bf16; bnapply reads xb;
//    prep merged into k_deg launch.
//   layer0: H,H8 = relu(x@Wr0 + segmean8(x8)@Wl0 + b0)
//   layer1: Pb = H@Wr1 + segmean8(H8)@Wl1 + b1 (+f32 BN stats);
//           H = bf16(relu(BN(Pb)) + xb)
//   layer2: {A64 = H@Wl2, Tb = H@Wr2 + b2}; out = log_softmax(segmean(A64)+Tb)
// ---------------------------------------------------------------------------

#define WS_EPS 1e-5f

typedef unsigned short ushort_t;
typedef unsigned int uint_t;
typedef unsigned char uchar_t;
typedef ushort_t ushort8 __attribute__((ext_vector_type(8)));
typedef short short8 __attribute__((ext_vector_type(8)));
typedef float f32x4 __attribute__((ext_vector_type(4)));
typedef _Float16 half2v __attribute__((ext_vector_type(2)));

__device__ __forceinline__ float bf2f(ushort_t u) {
    return __uint_as_float(((uint_t)u) << 16);
}
__device__ __forceinline__ ushort_t f2bf(float f) {
    uint_t u = __float_as_uint(f);
    u = (u + 0x7fffu + ((u >> 16) & 1u)) >> 16;  // RNE
    return (ushort_t)u;
}
// f32 -> OCP e4m3fn with flush-to-zero of subnormals (so decode is pure bit ops)
__device__ __forceinline__ uchar_t f2e4m3(float f) {
    _Float16 hf = (_Float16)f;  // RNE
    uint_t h = (uint_t)__builtin_bit_cast(unsigned short, hf);
    uint_t s = (h >> 8) & 0x80u;
    uint_t r = h & 0x7fffu;
    if (r < 0x2400u) return (uchar_t)0;   // |v| < 2^-6 -> 0
    if (r > 0x5F40u) r = 0x5F00u;         // clamp to 448
    uint_t u = r - 0x2000u;
    uint_t m = (u + 0x3fu + ((u >> 7) & 1u)) >> 7;  // RNE to 3-bit mantissa
    return (uchar_t)(s | m);
}

// ---- CSR build -------------------------------------------------------------
constexpr int SCHUNK = 4096;

__global__ __launch_bounds__(256) void k_scan_part(const int* __restrict__ deg,
                                                   int* __restrict__ bsum, int n) {
    int t = threadIdx.x;
    int base = blockIdx.x * SCHUNK + t * 16;
    int s = 0;
#pragma unroll
    for (int j = 0; j < 16; ++j) {
        int i = base + j;
        if (i < n) s += deg[i];
    }
#pragma unroll
    for (int d = 1; d < 64; d <<= 1) s += __shfl_xor(s, d);
    __shared__ int wt[4];
    if ((t & 63) == 0) wt[t >> 6] = s;
    __syncthreads();
    if (t == 0) bsum[blockIdx.x] = wt[0] + wt[1] + wt[2] + wt[3];
}

__global__ __launch_bounds__(64) void k_scan_bsum(const int* __restrict__ bsum,
                                                  int* __restrict__ boff,
                                                  int* __restrict__ off_n, int nb) {
    int lane = threadIdx.x;
    int carry = 0;
    for (int base = 0; base < nb; base += 64) {
        int t = base + lane;
        int v = (t < nb) ? bsum[t] : 0;
        int x = v;
#pragma unroll
        for (int d = 1; d < 64; d <<= 1) {
            int y = __shfl_up(x, d);
            if (lane >= d) x += y;
        }
        if (t < nb) boff[t] = carry + x - v;
        carry += __shfl(x, 63);
    }
    if (lane == 0) *off_n = carry;
}

__global__ __launch_bounds__(256) void k_scan_apply(const int* __restrict__ deg,
                                                    const int* __restrict__ boff,
                                                    int* __restrict__ off, int n) {
    int t = threadIdx.x;
    int lane = t & 63, wid = t >> 6;
    int base = blockIdx.x * SCHUNK + t * 16;
    int v[16];
    int s = 0;
#pragma unroll
    for (int j = 0; j < 16; ++j) {
        int i = base + j;
        v[j] = (i < n) ? deg[i] : 0;
        s += v[j];
    }
    int x = s;
#pragma unroll
    for (int d = 1; d < 64; d <<= 1) {
        int y = __shfl_up(x, d);
        if (lane >= d) x += y;
    }
    __shared__ int wtot[4];
    if (lane == 63) wtot[wid] = x;
    __syncthreads();
    int woff = 0;
    for (int wj = 0; wj < wid; ++wj) woff += wtot[wj];
    int run = boff[blockIdx.x] + woff + x - s;
#pragma unroll
    for (int j = 0; j < 16; ++j) {
        int i = base + j;
        if (i < n) off[i] = run;
        run += v[j];
    }
}

__global__ __launch_bounds__(256) void k_scatter(const int* __restrict__ ei,
                                                 const int* __restrict__ off,
                                                 int* __restrict__ cur,
                                                 int* __restrict__ csr, int E) {
    int e = blockIdx.x * 256 + threadIdx.x;
    if (e < E) {
        int d = ei[E + e];
        int s = ei[e];
        int p = atomicAdd(&cur[d], 1);
        csr[off[d] + p] = s;
    }
}

// ---- fused: degree count | x->bf16+fp8 | weights->bf16 transposed ----------
__global__ __launch_bounds__(256) void k_deg_prep(const int* __restrict__ ei,
                                                  int* __restrict__ deg, int E, int eb,
                                                  const float* __restrict__ x,
                                                  ushort_t* __restrict__ xb,
                                                  uchar_t* __restrict__ x8,
                                                  int total2, int nb_cvt,
                                                  const float* __restrict__ Wl0,
                                                  const float* __restrict__ Wr0,
                                                  const float* __restrict__ Wl1,
                                                  const float* __restrict__ Wr1,
                                                  const float* __restrict__ Wl2,
                                                  const float* __restrict__ Wr2,
                                                  ushort_t* __restrict__ wts) {
    int b = blockIdx.x;
    if (b < eb) {
        int e = b * 256 + threadIdx.x;
        if (e < E) atomicAdd(&deg[ei[E + e]], 1);
        return;
    }
    b -= eb;
    if (b < nb_cvt) {
        int i = b * 256 + threadIdx.x;
        if (i >= total2) return;
        float2 v = *(const float2*)&x[(size_t)i * 2];
        uint_t p = (uint_t)f2bf(v.x) | ((uint_t)f2bf(v.y) << 16);
        *(uint_t*)&xb[(size_t)i * 2] = p;
        ushort_t q = (ushort_t)((uint_t)f2e4m3(v.x) | ((uint_t)f2e4m3(v.y) << 8));
        *(ushort_t*)&x8[(size_t)i * 2] = q;
        return;
    }
    int id = (b - nb_cvt) * 256 + threadIdx.x;
    if (id >= 81920) return;
    const float* W;
    int rel, nout, base;
    if (id < 65536) {
        int m = id >> 14;
        rel = id & 16383;
        nout = 128;
        base = m << 14;
        W = (m == 0) ? Wl0 : (m == 1) ? Wr0 : (m == 2) ? Wl1 : Wr1;
    } else {
        int m = (id - 65536) >> 13;
        rel = (id - 65536) & 8191;
        nout = 64;
        base = 65536 + (m << 13);
        W = (m == 0) ? Wl2 : Wr2;
    }
    int c = rel >> 7;
    int k = rel & 127;
    wts[base + rel] = f2bf(W[(size_t)k * nout + c]);
}

// ---- dual GEMM, LDS-B, col-half split, 3-deep A prefetch --------------------
// out[n][128] = X1@W1 + X2@W2 + bias. B staged once (1 barrier).
// EPI: 2 -> relu, bf16 out + fp8 out8 (layer 0); 1 -> bf16 out + BN stats.
constexpr int LDK = 136;  // +8 pad: 16 cols spread over 8 bank-pairs

template <int EPI>
__global__ __launch_bounds__(256, 2) void k_dgemm(const ushort_t* __restrict__ X1,
                                                  const ushort_t* __restrict__ W1,
                                                  const ushort_t* __restrict__ X2,
                                                  const ushort_t* __restrict__ W2,
                                                  const float* __restrict__ bias,
                                                  ushort_t* __restrict__ outp,
                                                  uchar_t* __restrict__ out8,
                                                  float* __restrict__ stats, int n) {
    constexpr int K = 128, NOUT = 128;
    __shared__ ushort_t Bs[2 * 64 * LDK];  // [mat][col][k], 34.8 KB

    const int t = threadIdx.x;
    const int lane = t & 63;
    const int r16 = lane & 15, kb = lane >> 4;
    const int colbase = (blockIdx.x & 1) * 64;

    // stage this half's B tiles for both matrices (once)
#pragma unroll
    for (int u = 0; u < 8; ++u) {
        int f = u * 256 + t;
        int rel = f & 1023;
        int col = rel >> 4, seg = rel & 15;
        const ushort_t* Wm = (u < 4) ? W1 : W2;
        *(ushort8*)&Bs[(u < 4 ? 0 : 1) * 64 * LDK + col * LDK + seg * 8] =
            *(const ushort8*)&Wm[(size_t)(colbase + col) * K + seg * 8];
    }
    __syncthreads();

    float bcol[4];
#pragma unroll
    for (int fn = 0; fn < 4; ++fn) bcol[fn] = bias[colbase + fn * 16 + r16];
    float ssum[4] = {0.f, 0.f, 0.f, 0.f}, qsum[4] = {0.f, 0.f, 0.f, 0.f};

    const int strips = (n + 15) >> 4;
    const int wstr = (gridDim.x >> 1) * 4;
    const int s0 = (blockIdx.x >> 1) * 4 + (t >> 6);

    auto loadA = [&](short8* a, int s) {
        int arow = s * 16 + r16;
        bool ok = arow < n;
        size_t xo = (size_t)arow * K + kb * 8;
#pragma unroll
        for (int ks = 0; ks < 4; ++ks)
            a[ks] = ok ? *(const short8*)&X1[xo + ks * 32] : (short8)0;
#pragma unroll
        for (int ks = 0; ks < 4; ++ks)
            a[4 + ks] = ok ? *(const short8*)&X2[xo + ks * 32] : (short8)0;
    };

    auto work = [&](const short8* a, int s) {
        f32x4 acc[4] = {(f32x4)0.f, (f32x4)0.f, (f32x4)0.f, (f32x4)0.f};
#pragma unroll
        for (int ks = 0; ks < 4; ++ks) {
#pragma unroll
            for (int fn = 0; fn < 4; ++fn) {
                short8 b = *(const short8*)&Bs[(fn * 16 + r16) * LDK + ks * 32 + kb * 8];
                acc[fn] = __builtin_amdgcn_mfma_f32_16x16x32_bf16(a[ks], b, acc[fn], 0, 0, 0);
            }
        }
#pragma unroll
        for (int ks = 0; ks < 4; ++ks) {
#pragma unroll
            for (int fn = 0; fn < 4; ++fn) {
                short8 b = *(const short8*)&Bs[64 * LDK + (fn * 16 + r16) * LDK + ks * 32 + kb * 8];
                acc[fn] = __builtin_amdgcn_mfma_f32_16x16x32_bf16(a[4 + ks], b, acc[fn], 0, 0, 0);
            }
        }
        int rb = s * 16 + kb * 4;
#pragma unroll
        for (int r = 0; r < 4; ++r) {
            int row = rb + r;
            if (row >= n) continue;
#pragma unroll
            for (int fn = 0; fn < 4; ++fn) {
                int col = colbase + fn * 16 + r16;
                float v = acc[fn][r] + bcol[fn];
                if constexpr (EPI == 2) {
                    float rv = fmaxf(v, 0.f);
                    outp[(size_t)row * NOUT + col] = f2bf(rv);
                    out8[(size_t)row * NOUT + col] = f2e4m3(rv);
                } else {
                    outp[(size_t)row * NOUT + col] = f2bf(v);
                    ssum[fn] += v;
                    qsum[fn] += v * v;
                }
            }
        }
    };

    short8 aA[8], aB[8], aC[8];
    int s = s0;
    if (s < strips) {
        loadA(aA, s);
        int sB = s + wstr;
        bool vB = sB < strips;
        if (vB) loadA(aB, sB);
        for (;;) {
            int sC = sB + wstr;
            bool vC = vB && (sC < strips);
            if (vC) loadA(aC, sC);
            work(aA, s);
            if (!vB) break;
            int sD = sC + wstr;
            bool vD = vC && (sD < strips);
            if (vD) loadA(aA, sD);
            work(aB, sB);
            if (!vC) break;
            int sE = sD + wstr;
            bool vE = vD && (sE < strips);
            if (vE) loadA(aB, sE);
            work(aC, sC);
            if (!vD) break;
            s = sD;
            sB = sE;
            vB = vE;
        }
    }

    if constexpr (EPI == 1) {
#pragma unroll
        for (int fn = 0; fn < 4; ++fn) {
            ssum[fn] += __shfl_xor(ssum[fn], 16);
            ssum[fn] += __shfl_xor(ssum[fn], 32);
            qsum[fn] += __shfl_xor(qsum[fn], 16);
            qsum[fn] += __shfl_xor(qsum[fn], 32);
        }
        if (kb == 0) {
#pragma unroll
            for (int fn = 0; fn < 4; ++fn) {
                int col = colbase + fn * 16 + r16;
                atomicAdd(&stats[col], ssum[fn]);
                atomicAdd(&stats[128 + col], qsum[fn]);
            }
        }
    }
}

// ---- layer-2 GEMM: A64 = H@Wl2 (bf16), Tb = H@Wr2 + b2 (bf16) --------------
__global__ __launch_bounds__(256, 2) void k_cgemm(const ushort_t* __restrict__ H,
                                                  const ushort_t* __restrict__ WL,
                                                  const ushort_t* __restrict__ WR,
                                                  const float* __restrict__ b2,
                                                  ushort_t* __restrict__ A64,
                                                  ushort_t* __restrict__ Tb, int n) {
    constexpr int K = 128;
    __shared__ ushort_t Bs[2 * 64 * LDK];

    const int t = threadIdx.x;
    const int lane = t & 63;
    const int r16 = lane & 15, kb = lane >> 4;

#pragma unroll
    for (int u = 0; u < 8; ++u) {
        int f = u * 256 + t;
        int rel = f & 1023;
        int col = rel >> 4, seg = rel & 15;
        const ushort_t* Wm = (u < 4) ? WL : WR;
        *(ushort8*)&Bs[(u < 4 ? 0 : 1) * 64 * LDK + col * LDK + seg * 8] =
            *(const ushort8*)&Wm[(size_t)col * K + seg * 8];
    }
    __syncthreads();

    float bcol[4];
#pragma unroll
    for (int fn = 0; fn < 4; ++fn) bcol[fn] = b2[fn * 16 + r16];

    const int strips = (n + 15) >> 4;
    const int wstr = gridDim.x * 4;
    const int s0 = blockIdx.x * 4 + (t >> 6);

    auto loadA = [&](short8* a, int s) {
        int arow = s * 16 + r16;
        bool ok = arow < n;
        size_t xo = (size_t)arow * K + kb * 8;
#pragma unroll
        for (int ks = 0; ks < 4; ++ks)
            a[ks] = ok ? *(const short8*)&H[xo + ks * 32] : (short8)0;
    };

    auto work = [&](const short8* a, int s) {
        f32x4 aL[4] = {(f32x4)0.f, (f32x4)0.f, (f32x4)0.f, (f32x4)0.f};
        f32x4 aR[4] = {(f32x4)0.f, (f32x4)0.f, (f32x4)0.f, (f32x4)0.f};
#pragma unroll
        for (int ks = 0; ks < 4; ++ks) {
#pragma unroll
            for (int fn = 0; fn < 4; ++fn) {
                short8 bl = *(const short8*)&Bs[(fn * 16 + r16) * LDK + ks * 32 + kb * 8];
                short8 br = *(const short8*)&Bs[64 * LDK + (fn * 16 + r16) * LDK + ks * 32 + kb * 8];
                aL[fn] = __builtin_amdgcn_mfma_f32_16x16x32_bf16(a[ks], bl, aL[fn], 0, 0, 0);
                aR[fn] = __builtin_amdgcn_mfma_f32_16x16x32_bf16(a[ks], br, aR[fn], 0, 0, 0);
            }
        }
        int rb = s * 16 + kb * 4;
#pragma unroll
        for (int r = 0; r < 4; ++r) {
            int row = rb + r;
            if (row >= n) continue;
#pragma unroll
            for (int fn = 0; fn < 4; ++fn) {
                int col = fn * 16 + r16;
                A64[(size_t)row * 64 + col] = f2bf(aL[fn][r]);
                Tb[(size_t)row * 64 + col] = f2bf(aR[fn][r] + bcol[fn]);
            }
        }
    };

    short8 aA[4], aB[4], aC[4];
    int s = s0;
    if (s < strips) {
        loadA(aA, s);
        int sB = s + wstr;
        bool vB = sB < strips;
        if (vB) loadA(aB, sB);
        for (;;) {
            int sC = sB + wstr;
            bool vC = vB && (sC < strips);
            if (vC) loadA(aC, sC);
            work(aA, s);
            if (!vB) break;
            int sD = sC + wstr;
            bool vD = vC && (sD < strips);
            if (vD) loadA(aA, sD);
            work(aB, sB);
            if (!vC) break;
            int sE = sD + wstr;
            bool vE = vD && (sE < strips);
            if (vE) loadA(aB, sE);
            work(aC, sC);
            if (!vD) break;
            s = sD;
            sB = sE;
            vB = vE;
        }
    }
}

// ---- segment mean over CSR, fp8 in -> bf16 out. 8 lanes/node, 16 ch/lane ---
__global__ __launch_bounds__(256) void k_segmean8(const uchar_t* __restrict__ U8,
                                                  const int* __restrict__ off,
                                                  const int* __restrict__ srcs,
                                                  ushort_t* __restrict__ out, int n) {
    int node = blockIdx.x * 32 + (threadIdx.x >> 3);
    int sub = threadIdx.x & 7;
    if (node >= n) return;
    int beg = off[node], end = off[node + 1];
    half2v aE0 = (half2v)0, aE1 = (half2v)0, aE2 = (half2v)0, aE3 = (half2v)0;
    half2v aO0 = (half2v)0, aO1 = (half2v)0, aO2 = (half2v)0, aO3 = (half2v)0;

#define DEC(dw, AE, AO)                                                           \
    {                                                                             \
        uint_t xe = (dw)&0x00ff00ffu;                                             \
        uint_t xo = ((dw) >> 8) & 0x00ff00ffu;                                    \
        uint_t he = ((xe & 0x00800080u) << 8) |                                   \
                    (((xe & 0x007f007fu) << 7) + 0x20002000u);                    \
        uint_t ho = ((xo & 0x00800080u) << 8) |                                   \
                    (((xo & 0x007f007fu) << 7) + 0x20002000u);                    \
        AE += __builtin_bit_cast(half2v, he);                                     \
        AO += __builtin_bit_cast(half2v, ho);                                     \
    }

    auto addrow = [&](int sidx) {
        uint4 v = *(const uint4*)&U8[(size_t)sidx * 128 + sub * 16];
        DEC(v.x, aE0, aO0)
        DEC(v.y, aE1, aO1)
        DEC(v.z, aE2, aO2)
        DEC(v.w, aE3, aO3)
    };
#undef DEC

    int i = beg;
    for (; i + 8 <= end; i += 8) {
        int sv[8];
#pragma unroll
        for (int u = 0; u < 8; ++u) sv[u] = srcs[i + u];
#pragma unroll
        for (int u = 0; u < 8; ++u) addrow(sv[u]);
    }
    for (; i < end; ++i) addrow(srcs[i]);

    int d = end - beg;
    float inv = 1.f / (float)(d > 1 ? d : 1);
    ushort8 o0, o1;
#define PACK(AE, AO, O, IDX)                     \
    O[IDX] = f2bf((float)AE[0] * inv);           \
    O[IDX + 1] = f2bf((float)AO[0] * inv);       \
    O[IDX + 2] = f2bf((float)AE[1] * inv);       \
    O[IDX + 3] = f2bf((float)AO[1] * inv);
    PACK(aE0, aO0, o0, 0)
    PACK(aE1, aO1, o0, 4)
    PACK(aE2, aO2, o1, 0)
    PACK(aE3, aO3, o1, 4)
#undef PACK
    *(ushort8*)&out[(size_t)node * 128 + sub * 16] = o0;
    *(ushort8*)&out[(size_t)node * 128 + sub * 16 + 8] = o1;
}

// ---- fused 64-d segmean + log_softmax: out = lsm(segmean(A64) + Tb) --------
__global__ __launch_bounds__(256) void k_segmean_lsm(const ushort_t* __restrict__ A64,
                                                     const int* __restrict__ off,
                                                     const int* __restrict__ srcs,
                                                     const ushort_t* __restrict__ Tb,
                                                     float* __restrict__ out, int n) {
    int node = blockIdx.x * 32 + (threadIdx.x >> 3);
    int sub = threadIdx.x & 7;
    if (node >= n) return;  // whole 8-lane groups drop together
    int beg = off[node], end = off[node + 1];
    float a[8];
#pragma unroll
    for (int j = 0; j < 8; ++j) a[j] = 0.f;
    int i = beg;
    for (; i + 8 <= end; i += 8) {
        int sv[8];
#pragma unroll
        for (int u = 0; u < 8; ++u) sv[u] = srcs[i + u];
#pragma unroll
        for (int u = 0; u < 8; ++u) {
            ushort8 v = *(const ushort8*)&A64[(size_t)sv[u] * 64 + sub * 8];
#pragma unroll
            for (int j = 0; j < 8; ++j) a[j] += bf2f((ushort_t)v[j]);
        }
    }
    for (; i < end; ++i) {
        ushort8 v = *(const ushort8*)&A64[(size_t)srcs[i] * 64 + sub * 8];
#pragma unroll
        for (int j = 0; j < 8; ++j) a[j] += bf2f((ushort_t)v[j]);
    }
    int d = end - beg;
    float inv = 1.f / (float)(d > 1 ? d : 1);
    ushort8 tv = *(const ushort8*)&Tb[(size_t)node * 64 + sub * 8];
    float vv[8];
#pragma unroll
    for (int j = 0; j < 8; ++j) vv[j] = a[j] * inv + bf2f((ushort_t)tv[j]);
    float m = vv[0];
#pragma unroll
    for (int j = 1; j < 8; ++j) m = fmaxf(m, vv[j]);
#pragma unroll
    for (int dd = 1; dd < 8; dd <<= 1) m = fmaxf(m, __shfl_xor(m, dd));
    float e = 0.f;
#pragma unroll
    for (int j = 0; j < 8; ++j) e += expf(vv[j] - m);
#pragma unroll
    for (int dd = 1; dd < 8; dd <<= 1) e += __shfl_xor(e, dd);
    float lg = m + logf(e);
    f32x4 o0, o1;
#pragma unroll
    for (int j = 0; j < 4; ++j) {
        o0[j] = vv[j] - lg;
        o1[j] = vv[4 + j] - lg;
    }
    *(f32x4*)&out[(size_t)node * 64 + sub * 8] = o0;
    *(f32x4*)&out[(size_t)node * 64 + sub * 8 + 4] = o1;
}

// ---- BN apply + relu + residual (xb bf16), Pb bf16 -> H bf16 ---------------
__global__ __launch_bounds__(256) void k_bnapply(const ushort_t* __restrict__ P,
                                                 const ushort_t* __restrict__ Xb,
                                                 const float* __restrict__ stats,
                                                 const float* __restrict__ gamma,
                                                 const float* __restrict__ beta,
                                                 ushort_t* __restrict__ H, int n) {
    int i = blockIdx.x * 256 + threadIdx.x;  // one thread = 2 channels
    if (i >= n * 64) return;
    int nd = i >> 6;
    int c = (i & 63) << 1;
    float inv_n = 1.f / (float)n;
    float mu0 = stats[c] * inv_n, mu1 = stats[c + 1] * inv_n;
    float v0 = stats[128 + c] * inv_n - mu0 * mu0;
    float v1 = stats[128 + c + 1] * inv_n - mu1 * mu1;
    float s0 = rsqrtf(v0 + WS_EPS) * gamma[c];
    float s1 = rsqrtf(v1 + WS_EPS) * gamma[c + 1];
    uint_t pv = *(const uint_t*)&P[(size_t)nd * 128 + c];
    uint_t xv = *(const uint_t*)&Xb[(size_t)nd * 128 + c];
    float p0 = __uint_as_float(pv << 16);
    float p1 = __uint_as_float(pv & 0xffff0000u);
    float x0 = __uint_as_float(xv << 16);
    float x1 = __uint_as_float(xv & 0xffff0000u);
    float h0 = fmaxf((p0 - mu0) * s0 + beta[c], 0.f) + x0;
    float h1 = fmaxf((p1 - mu1) * s1 + beta[c + 1], 0.f) + x1;
    uint_t pk = (uint_t)f2bf(h0) | ((uint_t)f2bf(h1) << 16);
    *(uint_t*)&H[(size_t)nd * 128 + c] = pk;
}

// ---------------------------------------------------------------------------
extern "C" void kernel_launch(void* const* d_in, const int* in_sizes, int n_in,
                              void* d_out, int out_size, void* d_ws, size_t ws_size,
                              hipStream_t stream) {
    const float* x     = (const float*)d_in[0];
    const int*   ei    = (const int*)d_in[1];
    const float* Wl0   = (const float*)d_in[2];
    const float* Wr0   = (const float*)d_in[3];
    const float* b0    = (const float*)d_in[4];
    const float* Wl1   = (const float*)d_in[5];
    const float* Wr1   = (const float*)d_in[6];
    const float* b1    = (const float*)d_in[7];
    const float* Wl2   = (const float*)d_in[8];
    const float* Wr2   = (const float*)d_in[9];
    const float* b2    = (const float*)d_in[10];
    const float* gamma = (const float*)d_in[11];
    const float* beta  = (const float*)d_in[12];

    const int n = in_sizes[0] / 128;
    const int E = in_sizes[1] / 2;
    const int nb_scan = (n + SCHUNK - 1) / SCHUNK;

    char* w = (char*)d_ws;
    auto alloc = [&](size_t bytes) -> void* {
        void* p = (void*)w;
        w += (bytes + 255) & ~(size_t)255;
        return p;
    };
    int*      deg   = (int*)alloc((size_t)n * 4);
    int*      cur   = (int*)alloc((size_t)n * 4);
    float*    stats = (float*)alloc(256 * 4);
    size_t    zbytes = (size_t)((char*)w - (char*)deg);
    int*      off   = (int*)alloc(((size_t)n + 1) * 4);
    int*      csr   = (int*)alloc((size_t)E * 4);
    int*      bsum  = (int*)alloc(256 * 4);
    int*      boff  = (int*)alloc(256 * 4);
    ushort_t* wts   = (ushort_t*)alloc((size_t)81920 * 2);
    ushort_t* xb    = (ushort_t*)alloc((size_t)n * 128 * 2);
    uchar_t*  x8    = (uchar_t*)alloc((size_t)n * 128);
    ushort_t* H     = (ushort_t*)alloc((size_t)n * 128 * 2);
    uchar_t*  H8    = (uchar_t*)alloc((size_t)n * 128);
    ushort_t* Pb    = (ushort_t*)alloc((size_t)n * 128 * 2);
    ushort_t* M     = (ushort_t*)alloc((size_t)n * 128 * 2);
    ushort_t* A64   = (ushort_t*)alloc((size_t)n * 64 * 2);
    ushort_t* Tb    = (ushort_t*)alloc((size_t)n * 64 * 2);

    ushort_t* WtL0 = wts;
    ushort_t* WtR0 = wts + 16384;
    ushort_t* WtL1 = wts + 32768;
    ushort_t* WtR1 = wts + 49152;
    ushort_t* WtL2 = wts + 65536;
    ushort_t* WtR2 = wts + 73728;

    hipMemsetAsync(deg, 0, zbytes, stream);

    const int eb = (E + 255) / 256;
    const int nb_cvt = (n * 64 + 255) / 256;
    k_deg_prep<<<eb + nb_cvt + 320, 256, 0, stream>>>(ei, deg, E, eb, x, xb, x8,
                                                      n * 64, nb_cvt,
                                                      Wl0, Wr0, Wl1, Wr1, Wl2, Wr2, wts);
    k_scan_part<<<nb_scan, 256, 0, stream>>>(deg, bsum, n);
    k_scan_bsum<<<1, 64, 0, stream>>>(bsum, boff, off + n, nb_scan);
    k_scan_apply<<<nb_scan, 256, 0, stream>>>(deg, boff, off, n);
    k_scatter<<<(E + 255) / 256, 256, 0, stream>>>(ei, off, cur, csr, E);

    const int GB_D = 512;   // 2 halves x 256 block-streams (2 blocks/CU)
    const int GB_C = 256;
    const int smb = (n + 31) / 32;

    // layer 0: M = segmean(x8); H,H8 = relu(xb@Wr0 + M@Wl0 + b0)
    k_segmean8<<<smb, 256, 0, stream>>>(x8, off, csr, M, n);
    k_dgemm<2><<<GB_D, 256, 0, stream>>>(xb, WtR0, M, WtL0, b0, H, H8, nullptr, n);

    // layer 1: M = segmean(H8); Pb = H@Wr1 + M@Wl1 + b1 (+BN stats);
    //          H = bf16(relu(BN(Pb)) + xb)
    k_segmean8<<<smb, 256, 0, stream>>>(H8, off, csr, M, n);
    k_dgemm<1><<<GB_D, 256, 0, stream>>>(H, WtR1, M, WtL1, b1, Pb, nullptr, stats, n);
    k_bnapply<<<(n * 64 + 255) / 256, 256, 0, stream>>>(Pb, xb, stats, gamma, beta, H, n);

    // layer 2: {A64 = H@Wl2, Tb = H@Wr2 + b2}; out = lsm(segmean(A64) + Tb)
    k_cgemm<<<GB_C, 256, 0, stream>>>(H, WtL2, WtR2, b2, A64, Tb, n);
    k_segmean_lsm<<<smb, 256, 0, stream>>>(A64, off, csr, Tb, (float*)d_out, n);
}